// Round 17
// baseline (273.023 us; speedup 1.0000x reference)
//
#include <hip/hip_runtime.h>
#include <hip/hip_bf16.h>

typedef __attribute__((ext_vector_type(4))) float f32x4;
typedef __attribute__((ext_vector_type(16))) float f32x16;
typedef __attribute__((ext_vector_type(8))) short bf16x8;
typedef __attribute__((ext_vector_type(8))) int i32x8;
typedef unsigned short u16;
typedef unsigned char u8;

#define SEQ 2048
#define HID 1024
#define NROWS 16384

// ---------- helpers ----------
__device__ __forceinline__ float b2f(u16 u) {
    union { float f; unsigned i; } x; x.i = ((unsigned)u) << 16; return x.f;
}
__device__ __forceinline__ u16 f2b(float f) {
    unsigned x = __float_as_uint(f);
    return (u16)((x + 0x7fffu + ((x >> 16) & 1u)) >> 16);
}
// pack 4 floats -> 4 fp8 e4m3 (native v_cvt_pk_fp8_f32)
__device__ __forceinline__ unsigned pack4_fp8(float a, float b, float c, float d) {
    int v = 0;
    v = __builtin_amdgcn_cvt_pk_fp8_f32(a, b, v, false);
    v = __builtin_amdgcn_cvt_pk_fp8_f32(c, d, v, true);
    return (unsigned)v;
}
// decode fp8 e4m3 -> f32 (manual; subnormal handled)
__device__ __forceinline__ float fp8_to_f32(unsigned b) {
    unsigned s = b >> 7, e = (b >> 3) & 15u, m = b & 7u;
    float v = e ? __uint_as_float(((e + 120u) << 23) | (m << 20))
                : (float)m * 0.001953125f;   // m * 2^-9
    return s ? -v : v;
}
__device__ __forceinline__ void gload16(const void* g, void* l) {
    __builtin_amdgcn_global_load_lds(
        (const __attribute__((address_space(1))) void*)g,
        (__attribute__((address_space(3))) void*)l,
        16, 0, 0);
}

// ---------- fp32 -> bf16 convert ----------
__global__ __launch_bounds__(256)
void cvt_kernel(const float* __restrict__ src, u16* __restrict__ dst, int n) {
    int base = (blockIdx.x * 256 + threadIdx.x) * 4;
    if (base < n) {
        float4 v = *(const float4*)&src[base];
        ushort4 o;
        o.x = f2b(v.x); o.y = f2b(v.y); o.z = f2b(v.z); o.w = f2b(v.w);
        *(ushort4*)&dst[base] = o;
    }
}

// ---------- fp32 -> fp8 convert with scale ----------
__global__ __launch_bounds__(256)
void cvt_fp8_kernel(const float* __restrict__ src, u8* __restrict__ dst, int n, float scale) {
    int base = (blockIdx.x * 256 + threadIdx.x) * 4;
    if (base < n) {
        float4 v = *(const float4*)&src[base];
        *(unsigned*)&dst[base] = pack4_fp8(v.x * scale, v.y * scale, v.z * scale, v.w * scale);
    }
}

// ---------- fp32 1024x1024 -> bf16 transposed ----------
__global__ __launch_bounds__(256)
void transpose_cvt_kernel(const float* __restrict__ src, u16* __restrict__ dst) {
    __shared__ u16 tile[64][66];
    const int j0 = blockIdx.y * 64;
    const int i0 = blockIdx.x * 64;
    const int tid = threadIdx.x;
#pragma unroll
    for (int k = 0; k < 16; ++k) {
        int idx = k * 256 + tid;
        int r = idx >> 6, c = idx & 63;
        tile[r][c] = f2b(src[(size_t)(j0 + r) * 1024 + i0 + c]);
    }
    __syncthreads();
#pragma unroll
    for (int k = 0; k < 16; ++k) {
        int idx = k * 256 + tid;
        int r = idx >> 6, c = idx & 63;
        dst[(size_t)(i0 + r) * 1024 + j0 + c] = tile[c][r];
    }
}

// ---------- bvpp[o] = dot(Wp[o][:], bv) + bp[o] ----------
__global__ __launch_bounds__(64)
void bvp_kernel(const float* __restrict__ Wp, const float* __restrict__ bv,
                const float* __restrict__ bp, float* __restrict__ bvpp) {
    const int lane = threadIdx.x;
    float bvv[16];
#pragma unroll
    for (int i = 0; i < 16; ++i) bvv[i] = bv[lane + i * 64];
#pragma unroll
    for (int q = 0; q < 4; ++q) {
        const int o = blockIdx.x * 4 + q;
        float s = 0.f;
#pragma unroll
        for (int i = 0; i < 16; ++i) s += Wp[(size_t)o * 1024 + lane + i * 64] * bvv[i];
#pragma unroll
        for (int off = 32; off; off >>= 1) s += __shfl_xor(s, off);
        if (!lane) bvpp[o] = s + bp[o];
    }
}

// ---------- fp8 MX GEMM: 128x128 tile, BK=64, 256 thr (R15-validated) ----------
// mfma_scale_f32_32x32x64_f8f6f4, UNIT scales (E8M0 0x7F = 1.0).
// 4 waves (2Mx2N, 64x64/wave), LDS 2buf x 16KB = 32KB, 3 blocks/CU.
// OUTMODE 0: bf16 out; 4: fp8 out (batch: C+=bz*sC, bias+=bz*ldc);
// OUTMODE 1: fp8 transposed vT; OUTMODE 2: fp32 + bias + resid (rows bz*sC)
template<int OUTMODE>
__global__ __launch_bounds__(256, 3)
void gemm_fp8_kernel(const u8* __restrict__ A, const u8* __restrict__ B,
                     void* __restrict__ C,
                     const float* __restrict__ bias,
                     const float* __restrict__ resid,
                     float scale, int K,
                     long long sA, long long sB, long long sC,
                     int ldc)
{
    const unsigned nwg = gridDim.x * gridDim.y * gridDim.z;
    const unsigned bid = blockIdx.x + gridDim.x * (blockIdx.y + gridDim.y * blockIdx.z);
    const unsigned work = (bid & 7u) * (nwg >> 3) + (bid >> 3);
    const unsigned bx = work % gridDim.x;
    const unsigned rem = work / gridDim.x;
    const unsigned by = rem % gridDim.y;
    const unsigned bz = rem / gridDim.y;

    A += (long long)bz * sA;
    B += (long long)bz * sB;
    if (OUTMODE == 4 && bias) bias += (long long)bz * ldc;   // merged q/k bias

    const int tid  = threadIdx.x;
    const int lane = tid & 63;
    const int w    = tid >> 6;    // 0..3
    const int wm   = w >> 1;      // 0..1
    const int wn   = w & 1;       // 0..1
    const int l31  = lane & 31;
    const int hi   = lane >> 5;   // 0..1
    const int cc   = lane & 15;
    const int rg   = lane >> 4;   // 0..3

    const int m0 = by * 128;
    const int n0 = bx * 128;

    __shared__ u8 lds8[32768];    // 2 buf x (A 128x64B + B 128x64B)

    f32x16 acc[2][2] = {};
    i32x8 aF[2], bF[2];

    const int nk = K >> 6;

// chunk-permutation per row (both-sides involution, rule 21) — R12-validated
#define RX(R_) ((((R_) >> 1) & 3) ^ ((((R_) >> 3) & 1) << 1))

#define STAGE(tt, bsel) { \
    const int kb_ = (tt) << 6; \
    u8* Ad_ = &lds8[(bsel) * 16384]; \
    u8* Bd_ = Ad_ + 8192; \
    _Pragma("unroll") for (int j_ = 0; j_ < 2; ++j_) { \
        const int idx_ = j_ * 256 + tid; \
        const int r_ = idx_ >> 2, c_ = idx_ & 3; \
        const int so_ = ((c_ ^ RX(r_)) << 4); \
        gload16(A + (size_t)(m0 + r_) * K + kb_ + so_, &Ad_[r_ * 64 + c_ * 16]); \
        gload16(B + (size_t)(n0 + r_) * K + kb_ + so_, &Bd_[r_ * 64 + c_ * 16]); \
    } }

#define LOAD_FRAG(dst, P_, R_) { \
    const int rx_ = RX(R_); \
    uint4 lo_ = *(const uint4*)&P_[(R_) * 64 + (((hc2    ) ^ rx_) << 4)]; \
    uint4 hi_ = *(const uint4*)&P_[(R_) * 64 + (((hc2 + 1) ^ rx_) << 4)]; \
    dst[0] = (int)lo_.x; dst[1] = (int)lo_.y; dst[2] = (int)lo_.z; dst[3] = (int)lo_.w; \
    dst[4] = (int)hi_.x; dst[5] = (int)hi_.y; dst[6] = (int)hi_.z; dst[7] = (int)hi_.w; }

#define BAR()    __builtin_amdgcn_s_barrier()
#define SCHED0() __builtin_amdgcn_sched_barrier(0)
#define LGKM0()  { asm volatile("s_waitcnt lgkmcnt(0)" ::: "memory"); __builtin_amdgcn_sched_barrier(0); }
#define VM0()    asm volatile("s_waitcnt vmcnt(0)" ::: "memory")

    const int hc2 = hi << 1;   // 0 or 2: k-chunk base for this lane half

    STAGE(0, 0);

    for (int t = 0; t < nk; ++t) {
        VM0();
        BAR();
        SCHED0();
        if (t + 1 < nk) { STAGE(t + 1, (t + 1) & 1); SCHED0(); }
        const u8* Alp = &lds8[(t & 1) * 16384];
        const u8* Blp = Alp + 8192;
        LOAD_FRAG(bF[0], Blp, wn * 64 + l31);
        LOAD_FRAG(bF[1], Blp, wn * 64 + 32 + l31);
        LOAD_FRAG(aF[0], Alp, wm * 64 + l31);
        LOAD_FRAG(aF[1], Alp, wm * 64 + 32 + l31);
#pragma unroll
        for (int mi = 0; mi < 2; ++mi)
#pragma unroll
            for (int ni = 0; ni < 2; ++ni)
                acc[mi][ni] = __builtin_amdgcn_mfma_scale_f32_32x32x64_f8f6f4(
                    aF[mi], bF[ni], acc[mi][ni], 0, 0,
                    0, 0x7F7F7F7F, 0, 0x7F7F7F7F);
    }
    BAR();

    // ---- epilogues (32x32 C/D: col=lane&31, row=(reg&3)+8*(reg>>2)+4*hi) ----
    if constexpr (OUTMODE == 0 || OUTMODE == 2 || OUTMODE == 4) {
        float* ep = (float*)lds8 + w * 1088;  // [16][68] f32 per wave
        const int rcol = cc * 4;
        float4 b4 = make_float4(0.f, 0.f, 0.f, 0.f);
        if (bias) b4 = *(const float4*)&bias[n0 + wn * 64 + rcol];
#pragma unroll
        for (int mi = 0; mi < 2; ++mi)
#pragma unroll
        for (int p = 0; p < 2; ++p) {
#pragma unroll
            for (int ni = 0; ni < 2; ++ni)
#pragma unroll
                for (int d = 0; d < 8; ++d) {
                    const int rowp = (d & 3) + 8 * (d >> 2) + 4 * hi;  // 0..15
                    ep[rowp * 68 + ni * 32 + l31] = acc[mi][ni][p * 8 + d];
                }
            LGKM0();
#pragma unroll
            for (int j = 0; j < 4; ++j) {
                const int row = j * 4 + rg;
                float4 v = *(const float4*)&ep[row * 68 + rcol];
                const int gr = m0 + wm * 64 + mi * 32 + p * 16 + row;
                const int gc = n0 + wn * 64 + rcol;
                float4 ov;
                ov.x = v.x * scale + b4.x;
                ov.y = v.y * scale + b4.y;
                ov.z = v.z * scale + b4.z;
                ov.w = v.w * scale + b4.w;
                if constexpr (OUTMODE == 0) {
                    u16* Cb = (u16*)C + (long long)bz * sC;
                    ushort4 pk;
                    pk.x = f2b(ov.x); pk.y = f2b(ov.y); pk.z = f2b(ov.z); pk.w = f2b(ov.w);
                    *(ushort4*)&Cb[(size_t)gr * ldc + gc] = pk;
                } else if constexpr (OUTMODE == 4) {
                    u8* C8 = (u8*)C + (long long)bz * sC;
                    *(unsigned*)&C8[(size_t)gr * ldc + gc] = pack4_fp8(ov.x, ov.y, ov.z, ov.w);
                } else {
                    float* Cf = (float*)C;
                    size_t o = ((size_t)bz * sC + gr) * ldc + gc;
                    float4 rv = *(const float4*)&resid[o];
                    ov.x += rv.x; ov.y += rv.y; ov.z += rv.z; ov.w += rv.w;
                    *(float4*)&Cf[o] = ov;
                }
            }
            LGKM0();
        }
    } else {
        // OUTMODE 1: vT[b][col][s] fp8 — per-wave [64 cols][64B s], 16B XOR swizzle
        u8* epW = &lds8[w * 4096];
        const int colb = n0 + wn * 64;
#pragma unroll
        for (int ni = 0; ni < 2; ++ni) {
            const int col = ni * 32 + l31;
            const int cs = col & 3;
#pragma unroll
            for (int mi = 0; mi < 2; ++mi)
#pragma unroll
                for (int g = 0; g < 4; ++g) {
                    unsigned p32 = pack4_fp8(acc[mi][ni][4 * g]     * scale,
                                             acc[mi][ni][4 * g + 1] * scale,
                                             acc[mi][ni][4 * g + 2] * scale,
                                             acc[mi][ni][4 * g + 3] * scale);
                    const int chunk = 2 * mi + (g >> 1);
                    *(unsigned*)&epW[col * 64 + ((chunk ^ cs) << 4) + ((g & 1) << 3) + (hi << 2)] = p32;
                }
        }
        LGKM0();
        const int b  = (m0 + wm * 64) >> 11;
        const int sb = (m0 + wm * 64) & 2047;
        u8* Vb = (u8*)C;
#pragma unroll
        for (int j = 0; j < 4; ++j) {
            const int col = j * 16 + (lane >> 2);
            const int sch = lane & 3;
            uint4 vv = *(const uint4*)&epW[col * 64 + ((sch ^ (col & 3)) << 4)];
            *(uint4*)&Vb[((size_t)b * HID + colb + col) * SEQ + sb + sch * 16] = vv;
        }
    }
#undef STAGE
#undef LOAD_FRAG
#undef RX
#undef BAR
#undef SCHED0
#undef LGKM0
#undef VM0
}

// ---------- bf16 128x128 GEMM for Wvp = Wp @ Wv, fp8 out x64 ----------
__global__ __launch_bounds__(256, 2)
void gemm128_kernel(const u16* __restrict__ A, const u16* __restrict__ B,
                    u8* __restrict__ C, int K, int ldc, float oscale)
{
    const unsigned nwg = gridDim.x * gridDim.y;
    const unsigned bid = blockIdx.x + gridDim.x * blockIdx.y;
    const unsigned work = (bid & 7u) * (nwg >> 3) + (bid >> 3);
    const unsigned bx = work % gridDim.x;
    const unsigned by = work / gridDim.x;

    const int tid  = threadIdx.x;
    const int lane = tid & 63;
    const int w    = tid >> 6;
    const int wm   = w >> 1;
    const int wn   = w & 1;
    const int fr   = lane & 15;
    const int kg   = lane >> 4;
    const int swz  = (fr & 7) << 3;

    const int m0 = by * 128;
    const int n0 = bx * 128;

    __shared__ u16 lds[32768];

    f32x4 acc[4][4] = {};
    bf16x8 a0[4], a1[4], b0[4], b1[4];

    const int sr  = tid >> 3;
    const int sc8 = (tid & 7) << 3;
    const int nk = K >> 6;

#define STAGE(tt, bsel) { \
    const int kb_ = (tt) << 6; \
    u16* Ad_ = &lds[(bsel) * 16384]; \
    u16* Bd_ = Ad_ + 8192; \
    _Pragma("unroll") for (int j_ = 0; j_ < 4; ++j_) { \
        const int row_ = j_ * 32 + sr; \
        const int scb_ = sc8 ^ ((row_ & 7) << 3); \
        gload16(A + (size_t)(m0 + row_) * K + kb_ + scb_, &Ad_[row_ * 64 + sc8]); \
        gload16(B + (size_t)(n0 + row_) * K + kb_ + scb_, &Bd_[row_ * 64 + sc8]); \
    } }

#define READ_A(dst, ks) { const int cb_ = (((ks) << 5) | (kg << 3)) ^ swz; \
    _Pragma("unroll") for (int i_ = 0; i_ < 4; ++i_) \
      dst[i_] = *(const bf16x8*)&Alp[(wm * 64 + i_ * 16 + fr) * 64 + cb_]; }

#define READ_B(dst, ks) { const int cb_ = (((ks) << 5) | (kg << 3)) ^ swz; \
    _Pragma("unroll") for (int n_ = 0; n_ < 4; ++n_) \
      dst[n_] = *(const bf16x8*)&Blp[(wn * 64 + n_ * 16 + fr) * 64 + cb_]; }

#define MFMA_TILE(aset, bset) \
    _Pragma("unroll") for (int i_ = 0; i_ < 4; ++i_) \
      _Pragma("unroll") for (int n_ = 0; n_ < 4; ++n_) \
        acc[i_][n_] = __builtin_amdgcn_mfma_f32_16x16x32_bf16(aset[i_], bset[n_], acc[i_][n_], 0, 0, 0);

    STAGE(0, 0);
    for (int t = 0; t < nk; ++t) {
        asm volatile("s_waitcnt vmcnt(0)" ::: "memory");
        __builtin_amdgcn_s_barrier();
        __builtin_amdgcn_sched_barrier(0);
        if (t + 1 < nk) { STAGE(t + 1, (t + 1) & 1); __builtin_amdgcn_sched_barrier(0); }
        const u16* Alp = &lds[(t & 1) * 16384];
        const u16* Blp = Alp + 8192;
        READ_B(b0, 0); READ_A(a0, 0);
        MFMA_TILE(a0, b0);
        READ_B(b1, 1); READ_A(a1, 1);
        MFMA_TILE(a1, b1);
    }
    __builtin_amdgcn_s_barrier();

    const int cc = lane & 15;
    const int rg = lane >> 4;
    float* ep = (float*)lds + w * 1088;
    const int rcol = cc * 4;
#pragma unroll
    for (int m = 0; m < 4; ++m) {
#pragma unroll
        for (int n = 0; n < 4; ++n)
#pragma unroll
            for (int r = 0; r < 4; ++r)
                ep[(rg * 4 + r) * 68 + n * 16 + cc] = acc[m][n][r];
        asm volatile("s_waitcnt lgkmcnt(0)" ::: "memory");
        __builtin_amdgcn_sched_barrier(0);
#pragma unroll
        for (int j = 0; j < 4; ++j) {
            const int row = j * 4 + rg;
            float4 v = *(const float4*)&ep[row * 68 + rcol];
            const int gr = m0 + wm * 64 + m * 16 + row;
            *(unsigned*)&C[(size_t)gr * ldc + n0 + wn * 64 + rcol] =
                pack4_fp8(v.x * oscale, v.y * oscale, v.z * oscale, v.w * oscale);
        }
        asm volatile("s_waitcnt lgkmcnt(0)" ::: "memory");
        __builtin_amdgcn_sched_barrier(0);
    }
#undef STAGE
#undef READ_A
#undef READ_B
#undef MFMA_TILE
}

// ---------- row softmax: fp8 scores in, fp8 probs*1024 out ----------
__global__ __launch_bounds__(256)
void softmax_kernel(const u8* __restrict__ sc, u8* __restrict__ pr) {
    const size_t row = blockIdx.x;
    const u8* p = sc + row * 2048;
    const int tid = threadIdx.x;
    const int lane = tid & 63;
    const int w = tid >> 6;

    uint2 raw = *(const uint2*)&p[tid * 8];
    float v[8];
#pragma unroll
    for (int j = 0; j < 4; ++j) v[j]     = fp8_to_f32((raw.x >> (8 * j)) & 0xFF);
#pragma unroll
    for (int j = 0; j < 4; ++j) v[4 + j] = fp8_to_f32((raw.y >> (8 * j)) & 0xFF);

    float mx = v[0];
#pragma unroll
    for (int j = 1; j < 8; ++j) mx = fmaxf(mx, v[j]);
#pragma unroll
    for (int o = 32; o; o >>= 1) mx = fmaxf(mx, __shfl_xor(mx, o));

    __shared__ float red[8];
    if (!lane) red[w] = mx;
    __syncthreads();
    mx = fmaxf(fmaxf(red[0], red[1]), fmaxf(red[2], red[3]));

    float s = 0.f;
#pragma unroll
    for (int j = 0; j < 8; ++j) { v[j] = __expf(v[j] - mx); s += v[j]; }
#pragma unroll
    for (int o = 32; o; o >>= 1) s += __shfl_xor(s, o);
    if (!lane) red[4 + w] = s;
    __syncthreads();
    s = red[4] + red[5] + red[6] + red[7];
    float inv = 1024.0f / s;   // scale probs by 1024 (fp8 subnormal floor)

    uint2 o8;
    o8.x = pack4_fp8(v[0] * inv, v[1] * inv, v[2] * inv, v[3] * inv);
    o8.y = pack4_fp8(v[4] * inv, v[5] * inv, v[6] * inv, v[7] * inv);
    *(uint2*)&pr[row * 2048 + tid * 8] = o8;
}

// ---------- in-place LayerNorm over rows of 1024 fp32 ----------
__global__ __launch_bounds__(256)
void layernorm_kernel(float* __restrict__ y,
                      const float* __restrict__ gamma,
                      const float* __restrict__ beta) {
    const size_t row = blockIdx.x;
    float* p = y + row * 1024;
    const int tid = threadIdx.x;
    const int lane = tid & 63;
    const int w = tid >> 6;

    float4 v = *(const float4*)&p[tid * 4];
    float s = v.x + v.y + v.z + v.w;
    float q = v.x * v.x + v.y * v.y + v.z * v.z + v.w * v.w;
#pragma unroll
    for (int o = 32; o; o >>= 1) { s += __shfl_xor(s, o); q += __shfl_xor(q, o); }

    __shared__ float red[16];
    if (!lane) { red[w] = s; red[8 + w] = q; }
    __syncthreads();
    s = red[0] + red[1] + red[2] + red[3];
    q = red[8] + red[9] + red[10] + red[11];

    const float mu  = s * (1.0f / 1024.0f);
    const float var = q * (1.0f / 1024.0f) - mu * mu;
    const float rs  = rsqrtf(var + 1e-5f);

    float4 g  = *(const float4*)&gamma[tid * 4];
    float4 be = *(const float4*)&beta[tid * 4];
    float4 o;
    o.x = (v.x - mu) * rs * g.x + be.x;
    o.y = (v.y - mu) * rs * g.y + be.y;
    o.z = (v.z - mu) * rs * g.z + be.z;
    o.w = (v.w - mu) * rs * g.w + be.w;
    *(float4*)&p[tid * 4] = o;
}

extern "C" void kernel_launch(void* const* d_in, const int* in_sizes, int n_in,
                              void* d_out, int out_size, void* d_ws, size_t ws_size,
                              hipStream_t stream) {
    const float* x     = (const float*)d_in[0];
    const float* Wq    = (const float*)d_in[1];
    const float* bq    = (const float*)d_in[2];
    const float* Wk    = (const float*)d_in[3];
    const float* bk    = (const float*)d_in[4];
    const float* Wv    = (const float*)d_in[5];
    const float* bv    = (const float*)d_in[6];
    const float* Wp    = (const float*)d_in[7];
    const float* bp    = (const float*)d_in[8];
    const float* gamma = (const float*)d_in[9];
    const float* beta  = (const float*)d_in[10];
    float* out = (float*)d_out;

    char* ws = (char*)d_ws;
    u8*    x8      = (u8*)(ws + 0);             // 16 MB
    u8*    q8      = (u8*)(ws + 16777216);      // 16 MB  (q8 || k8 contiguous)
    u8*    k8      = (u8*)(ws + 33554432);      // 16 MB
    u8*    vT8     = (u8*)(ws + 50331648);      // 16 MB [8][1024][2048]
    u8*    probs8  = (u8*)(ws + 67108864);      // 32 MB
    u8*    scores8 = (u8*)(ws + 100663296);     // 32 MB [8][2048][2048] fp8
    u8*    wq8     = (u8*)(ws + 167772160);     // 1 MB  (wq8 || wk8 contiguous)
    u8*    wk8     = (u8*)(ws + 168820736);     // 1 MB
    u8*    wvp8    = (u8*)(ws + 169869312);     // 1 MB
    u16*   wpb     = (u16*)(ws + 170917888);    // 2 MB
    u16*   wvT     = (u16*)(ws + 173015040);    // 2 MB
    float* bvpp    = (float*)(ws + 175112192);  // 4 KB
    float* bqk     = (float*)(ws + 175116288);  // 8 KB: bq || bk

    // concatenated q/k bias for the merged projection dispatch
    hipMemcpyAsync(bqk,        bq, 1024 * sizeof(float), hipMemcpyDeviceToDevice, stream);
    hipMemcpyAsync(bqk + 1024, bk, 1024 * sizeof(float), hipMemcpyDeviceToDevice, stream);

    // precompute Wvp (=Wp@Wv, x64 fp8) and bvpp (=Wp@bv + bp)
    cvt_kernel<<<1024, 256, 0, stream>>>(Wp, wpb, HID * HID);
    transpose_cvt_kernel<<<dim3(16, 16), 256, 0, stream>>>(Wv, wvT);
    bvp_kernel<<<256, 64, 0, stream>>>(Wp, bv, bp, bvpp);
    gemm128_kernel<<<dim3(8, 8), 256, 0, stream>>>(wpb, wvT, wvp8, HID, HID, 64.0f);

    // fp8 converts (weights pre-scaled x32 to clear e4m3 subnormal floor)
    cvt_fp8_kernel<<<16384, 256, 0, stream>>>(x,  x8,  NROWS * HID, 1.0f);
    cvt_fp8_kernel<<<1024, 256, 0, stream>>>(Wq, wq8, HID * HID, 32.0f);
    cvt_fp8_kernel<<<1024, 256, 0, stream>>>(Wk, wk8, HID * HID, 32.0f);

    dim3 blk(256);
    // merged q+k projection: z=0 -> q8 (bias bq), z=1 -> k8 (bias bk)
    // B strides through wq8||wk8 (1 MB), C through q8||k8 (16 MB)
    gemm_fp8_kernel<4><<<dim3(8, 128, 2), blk, 0, stream>>>(
        x8, wq8, q8, bqk, nullptr, 0.03125f, HID,
        0, (long long)HID * HID, 16777216LL, HID);
    // vp projection: vp = (x*64Wvp)/64 -> fp8, transposed vT8[b][h][s]
    gemm_fp8_kernel<1><<<dim3(8, 128, 1), blk, 0, stream>>>(
        x8, wvp8, vT8, nullptr, nullptr, 0.015625f, HID, 0, 0, 0, 0);

    // scores = (q.k)/32 -> fp8 (per batch)
    gemm_fp8_kernel<4><<<dim3(16, 16, 8), blk, 0, stream>>>(
        q8, k8, scores8, nullptr, nullptr, 0.03125f, HID,
        (long long)SEQ * HID, (long long)SEQ * HID, (long long)SEQ * SEQ, SEQ);

    softmax_kernel<<<NROWS, 256, 0, stream>>>(scores8, probs8);

    // out = (probs1024 . vp)/1024 + (bvp+bp) + x  (fp32)
    gemm_fp8_kernel<2><<<dim3(8, 16, 8), blk, 0, stream>>>(
        probs8, vT8, out, bvpp, x, 0.0009765625f, SEQ,
        (long long)SEQ * SEQ, (long long)HID * SEQ, (long long)SEQ, HID);

    layernorm_kernel<<<NROWS, 256, 0, stream>>>(out, gamma, beta);
}

// Round 18
// 262.311 us; speedup vs baseline: 1.0408x; 1.0408x over previous
//
#include <hip/hip_runtime.h>
#include <hip/hip_bf16.h>

typedef __attribute__((ext_vector_type(4))) float f32x4;
typedef __attribute__((ext_vector_type(16))) float f32x16;
typedef __attribute__((ext_vector_type(8))) short bf16x8;
typedef __attribute__((ext_vector_type(8))) int i32x8;
typedef unsigned short u16;
typedef unsigned char u8;

#define SEQ 2048
#define HID 1024
#define NROWS 16384

// ---------- helpers ----------
__device__ __forceinline__ float b2f(u16 u) {
    union { float f; unsigned i; } x; x.i = ((unsigned)u) << 16; return x.f;
}
__device__ __forceinline__ u16 f2b(float f) {
    unsigned x = __float_as_uint(f);
    return (u16)((x + 0x7fffu + ((x >> 16) & 1u)) >> 16);
}
__device__ __forceinline__ unsigned pack4_fp8(float a, float b, float c, float d) {
    int v = 0;
    v = __builtin_amdgcn_cvt_pk_fp8_f32(a, b, v, false);
    v = __builtin_amdgcn_cvt_pk_fp8_f32(c, d, v, true);
    return (unsigned)v;
}
__device__ __forceinline__ float fp8_to_f32(unsigned b) {
    unsigned s = b >> 7, e = (b >> 3) & 15u, m = b & 7u;
    float v = e ? __uint_as_float(((e + 120u) << 23) | (m << 20))
                : (float)m * 0.001953125f;
    return s ? -v : v;
}
__device__ __forceinline__ void gload16(const void* g, void* l) {
    __builtin_amdgcn_global_load_lds(
        (const __attribute__((address_space(1))) void*)g,
        (__attribute__((address_space(3))) void*)l,
        16, 0, 0);
}

// ---------- fp32 -> bf16 convert ----------
__global__ __launch_bounds__(256)
void cvt_kernel(const float* __restrict__ src, u16* __restrict__ dst, int n) {
    int base = (blockIdx.x * 256 + threadIdx.x) * 4;
    if (base < n) {
        float4 v = *(const float4*)&src[base];
        ushort4 o;
        o.x = f2b(v.x); o.y = f2b(v.y); o.z = f2b(v.z); o.w = f2b(v.w);
        *(ushort4*)&dst[base] = o;
    }
}

// ---------- fused fp32 -> fp8 convert for x / Wq / Wk (one dispatch) ----------
// blocks [0,16384): x (scale 1) ; [16384,17408): Wq (x32) ; [17408,18432): Wk (x32)
__global__ __launch_bounds__(256)
void cvt_fp8_fused_kernel(const float* __restrict__ x,  u8* __restrict__ x8,
                          const float* __restrict__ Wq, u8* __restrict__ wq8,
                          const float* __restrict__ Wk, u8* __restrict__ wk8) {
    const unsigned b = blockIdx.x;
    const float* src; u8* dst; float scale; unsigned base;
    if (b < 16384u)      { src = x;  dst = x8;  scale = 1.0f;  base = b; }
    else if (b < 17408u) { src = Wq; dst = wq8; scale = 32.0f; base = b - 16384u; }
    else                 { src = Wk; dst = wk8; scale = 32.0f; base = b - 17408u; }
    const unsigned idx = (base * 256 + threadIdx.x) * 4;
    float4 v = *(const float4*)&src[idx];
    *(unsigned*)&dst[idx] = pack4_fp8(v.x * scale, v.y * scale, v.z * scale, v.w * scale);
}

// ---------- fp32 1024x1024 -> bf16 transposed ----------
__global__ __launch_bounds__(256)
void transpose_cvt_kernel(const float* __restrict__ src, u16* __restrict__ dst) {
    __shared__ u16 tile[64][66];
    const int j0 = blockIdx.y * 64;
    const int i0 = blockIdx.x * 64;
    const int tid = threadIdx.x;
#pragma unroll
    for (int k = 0; k < 16; ++k) {
        int idx = k * 256 + tid;
        int r = idx >> 6, c = idx & 63;
        tile[r][c] = f2b(src[(size_t)(j0 + r) * 1024 + i0 + c]);
    }
    __syncthreads();
#pragma unroll
    for (int k = 0; k < 16; ++k) {
        int idx = k * 256 + tid;
        int r = idx >> 6, c = idx & 63;
        dst[(size_t)(i0 + r) * 1024 + j0 + c] = tile[c][r];
    }
}

// ---------- bvpp[o] = dot(Wp[o][:], bv) + bp[o] ----------
__global__ __launch_bounds__(64)
void bvp_kernel(const float* __restrict__ Wp, const float* __restrict__ bv,
                const float* __restrict__ bp, float* __restrict__ bvpp) {
    const int lane = threadIdx.x;
    float bvv[16];
#pragma unroll
    for (int i = 0; i < 16; ++i) bvv[i] = bv[lane + i * 64];
#pragma unroll
    for (int q = 0; q < 4; ++q) {
        const int o = blockIdx.x * 4 + q;
        float s = 0.f;
#pragma unroll
        for (int i = 0; i < 16; ++i) s += Wp[(size_t)o * 1024 + lane + i * 64] * bvv[i];
#pragma unroll
        for (int off = 32; off; off >>= 1) s += __shfl_xor(s, off);
        if (!lane) bvpp[o] = s + bp[o];
    }
}

// ---------- fp8 MX GEMM: 128x128 tile, BK=64, 256 thr (R15-validated) ----------
// mfma_scale_f32_32x32x64_f8f6f4, UNIT scales (E8M0 0x7F = 1.0).
// 4 waves (2Mx2N, 64x64/wave), LDS 2buf x 16KB = 32KB, 3 blocks/CU.
// OUTMODE 4: fp8 out (batch: C+=bz*sC, bias+=bz*ldc)
// OUTMODE 1: fp8 transposed vT[b][col][s]
// OUTMODE 2: fp32 out + bias + resid (rows bz*sC)
// OUTMODE 5: fused projections — bz<2: fp8 q/k (as 4); bz==2: vT (as 1,
//            dest = C2, scale 0.015625)
template<int OUTMODE>
__global__ __launch_bounds__(256, 3)
void gemm_fp8_kernel(const u8* __restrict__ A, const u8* __restrict__ B,
                     void* __restrict__ C, void* __restrict__ C2,
                     const float* __restrict__ bias,
                     const float* __restrict__ resid,
                     float scale, int K,
                     long long sA, long long sB, long long sC,
                     int ldc)
{
    const unsigned nwg = gridDim.x * gridDim.y * gridDim.z;
    const unsigned bid = blockIdx.x + gridDim.x * (blockIdx.y + gridDim.y * blockIdx.z);
    const unsigned work = (bid & 7u) * (nwg >> 3) + (bid >> 3);
    const unsigned bx = work % gridDim.x;
    const unsigned rem = work / gridDim.x;
    const unsigned by = rem % gridDim.y;
    const unsigned bz = rem / gridDim.y;

    A += (long long)bz * sA;
    B += (long long)bz * sB;
    if ((OUTMODE == 4 || OUTMODE == 5) && bias && bz < 2) bias += (long long)bz * ldc;

    const int tid  = threadIdx.x;
    const int lane = tid & 63;
    const int w    = tid >> 6;    // 0..3
    const int wm   = w >> 1;      // 0..1
    const int wn   = w & 1;       // 0..1
    const int l31  = lane & 31;
    const int hi   = lane >> 5;   // 0..1
    const int cc   = lane & 15;
    const int rg   = lane >> 4;   // 0..3

    const int m0 = by * 128;
    const int n0 = bx * 128;

    __shared__ u8 lds8[32768];    // 2 buf x (A 128x64B + B 128x64B)

    f32x16 acc[2][2] = {};
    i32x8 aF[2], bF[2];

    const int nk = K >> 6;

#define RX(R_) ((((R_) >> 1) & 3) ^ ((((R_) >> 3) & 1) << 1))

#define STAGE(tt, bsel) { \
    const int kb_ = (tt) << 6; \
    u8* Ad_ = &lds8[(bsel) * 16384]; \
    u8* Bd_ = Ad_ + 8192; \
    _Pragma("unroll") for (int j_ = 0; j_ < 2; ++j_) { \
        const int idx_ = j_ * 256 + tid; \
        const int r_ = idx_ >> 2, c_ = idx_ & 3; \
        const int so_ = ((c_ ^ RX(r_)) << 4); \
        gload16(A + (size_t)(m0 + r_) * K + kb_ + so_, &Ad_[r_ * 64 + c_ * 16]); \
        gload16(B + (size_t)(n0 + r_) * K + kb_ + so_, &Bd_[r_ * 64 + c_ * 16]); \
    } }

#define LOAD_FRAG(dst, P_, R_) { \
    const int rx_ = RX(R_); \
    uint4 lo_ = *(const uint4*)&P_[(R_) * 64 + (((hc2    ) ^ rx_) << 4)]; \
    uint4 hi_ = *(const uint4*)&P_[(R_) * 64 + (((hc2 + 1) ^ rx_) << 4)]; \
    dst[0] = (int)lo_.x; dst[1] = (int)lo_.y; dst[2] = (int)lo_.z; dst[3] = (int)lo_.w; \
    dst[4] = (int)hi_.x; dst[5] = (int)hi_.y; dst[6] = (int)hi_.z; dst[7] = (int)hi_.w; }

#define BAR()    __builtin_amdgcn_s_barrier()
#define SCHED0() __builtin_amdgcn_sched_barrier(0)
#define LGKM0()  { asm volatile("s_waitcnt lgkmcnt(0)" ::: "memory"); __builtin_amdgcn_sched_barrier(0); }
#define VM0()    asm volatile("s_waitcnt vmcnt(0)" ::: "memory")

    const int hc2 = hi << 1;

    STAGE(0, 0);

    for (int t = 0; t < nk; ++t) {
        VM0();
        BAR();
        SCHED0();
        if (t + 1 < nk) { STAGE(t + 1, (t + 1) & 1); SCHED0(); }
        const u8* Alp = &lds8[(t & 1) * 16384];
        const u8* Blp = Alp + 8192;
        LOAD_FRAG(bF[0], Blp, wn * 64 + l31);
        LOAD_FRAG(bF[1], Blp, wn * 64 + 32 + l31);
        LOAD_FRAG(aF[0], Alp, wm * 64 + l31);
        LOAD_FRAG(aF[1], Alp, wm * 64 + 32 + l31);
#pragma unroll
        for (int mi = 0; mi < 2; ++mi)
#pragma unroll
            for (int ni = 0; ni < 2; ++ni)
                acc[mi][ni] = __builtin_amdgcn_mfma_scale_f32_32x32x64_f8f6f4(
                    aF[mi], bF[ni], acc[mi][ni], 0, 0,
                    0, 0x7F7F7F7F, 0, 0x7F7F7F7F);
    }
    BAR();

    // ---- epilogues (32x32 C/D: col=lane&31, row=(reg&3)+8*(reg>>2)+4*hi) ----
    const bool rowmajor_path = (OUTMODE == 2 || OUTMODE == 4) || (OUTMODE == 5 && bz < 2);

    if (rowmajor_path) {
        float* ep = (float*)lds8 + w * 1088;  // [16][68] f32 per wave
        const int rcol = cc * 4;
        float4 b4 = make_float4(0.f, 0.f, 0.f, 0.f);
        if (bias) b4 = *(const float4*)&bias[n0 + wn * 64 + rcol];
#pragma unroll
        for (int mi = 0; mi < 2; ++mi)
#pragma unroll
        for (int p = 0; p < 2; ++p) {
#pragma unroll
            for (int ni = 0; ni < 2; ++ni)
#pragma unroll
                for (int d = 0; d < 8; ++d) {
                    const int rowp = (d & 3) + 8 * (d >> 2) + 4 * hi;
                    ep[rowp * 68 + ni * 32 + l31] = acc[mi][ni][p * 8 + d];
                }
            LGKM0();
#pragma unroll
            for (int j = 0; j < 4; ++j) {
                const int row = j * 4 + rg;
                float4 v = *(const float4*)&ep[row * 68 + rcol];
                const int gr = m0 + wm * 64 + mi * 32 + p * 16 + row;
                const int gc = n0 + wn * 64 + rcol;
                float4 ov;
                ov.x = v.x * scale + b4.x;
                ov.y = v.y * scale + b4.y;
                ov.z = v.z * scale + b4.z;
                ov.w = v.w * scale + b4.w;
                if constexpr (OUTMODE == 2) {
                    float* Cf = (float*)C;
                    size_t o = ((size_t)bz * sC + gr) * ldc + gc;
                    float4 rv = *(const float4*)&resid[o];
                    ov.x += rv.x; ov.y += rv.y; ov.z += rv.z; ov.w += rv.w;
                    *(float4*)&Cf[o] = ov;
                } else {
                    u8* C8 = (u8*)C + (long long)bz * sC;
                    *(unsigned*)&C8[(size_t)gr * ldc + gc] = pack4_fp8(ov.x, ov.y, ov.z, ov.w);
                }
            }
            LGKM0();
        }
    } else {
        // transposed vT[b][col][s] fp8 — per-wave [64 cols][64B s], 16B XOR swizzle
        const float vs = (OUTMODE == 5) ? 0.015625f : scale;
        u8* epW = &lds8[w * 4096];
        const int colb = n0 + wn * 64;
#pragma unroll
        for (int ni = 0; ni < 2; ++ni) {
            const int col = ni * 32 + l31;
            const int cs = col & 3;
#pragma unroll
            for (int mi = 0; mi < 2; ++mi)
#pragma unroll
                for (int g = 0; g < 4; ++g) {
                    unsigned p32 = pack4_fp8(acc[mi][ni][4 * g]     * vs,
                                             acc[mi][ni][4 * g + 1] * vs,
                                             acc[mi][ni][4 * g + 2] * vs,
                                             acc[mi][ni][4 * g + 3] * vs);
                    const int chunk = 2 * mi + (g >> 1);
                    *(unsigned*)&epW[col * 64 + ((chunk ^ cs) << 4) + ((g & 1) << 3) + (hi << 2)] = p32;
                }
        }
        LGKM0();
        const int b  = (m0 + wm * 64) >> 11;
        const int sb = (m0 + wm * 64) & 2047;
        u8* Vb = (OUTMODE == 5) ? (u8*)C2 : (u8*)C;
#pragma unroll
        for (int j = 0; j < 4; ++j) {
            const int col = j * 16 + (lane >> 2);
            const int sch = lane & 3;
            uint4 vv = *(const uint4*)&epW[col * 64 + ((sch ^ (col & 3)) << 4)];
            *(uint4*)&Vb[((size_t)b * HID + colb + col) * SEQ + sb + sch * 16] = vv;
        }
    }
#undef STAGE
#undef LOAD_FRAG
#undef RX
#undef BAR
#undef SCHED0
#undef LGKM0
#undef VM0
}

// ---------- bf16 128x128 GEMM for Wvp = Wp @ Wv, fp8 out x64 ----------
__global__ __launch_bounds__(256, 2)
void gemm128_kernel(const u16* __restrict__ A, const u16* __restrict__ B,
                    u8* __restrict__ C, int K, int ldc, float oscale)
{
    const unsigned nwg = gridDim.x * gridDim.y;
    const unsigned bid = blockIdx.x + gridDim.x * blockIdx.y;
    const unsigned work = (bid & 7u) * (nwg >> 3) + (bid >> 3);
    const unsigned bx = work % gridDim.x;
    const unsigned by = work / gridDim.x;

    const int tid  = threadIdx.x;
    const int lane = tid & 63;
    const int w    = tid >> 6;
    const int wm   = w >> 1;
    const int wn   = w & 1;
    const int fr   = lane & 15;
    const int kg   = lane >> 4;
    const int swz  = (fr & 7) << 3;

    const int m0 = by * 128;
    const int n0 = bx * 128;

    __shared__ u16 lds[32768];

    f32x4 acc[4][4] = {};
    bf16x8 a0[4], a1[4], b0[4], b1[4];

    const int sr  = tid >> 3;
    const int sc8 = (tid & 7) << 3;
    const int nk = K >> 6;

#define STAGE(tt, bsel) { \
    const int kb_ = (tt) << 6; \
    u16* Ad_ = &lds[(bsel) * 16384]; \
    u16* Bd_ = Ad_ + 8192; \
    _Pragma("unroll") for (int j_ = 0; j_ < 4; ++j_) { \
        const int row_ = j_ * 32 + sr; \
        const int scb_ = sc8 ^ ((row_ & 7) << 3); \
        gload16(A + (size_t)(m0 + row_) * K + kb_ + scb_, &Ad_[row_ * 64 + sc8]); \
        gload16(B + (size_t)(n0 + row_) * K + kb_ + scb_, &Bd_[row_ * 64 + sc8]); \
    } }

#define READ_A(dst, ks) { const int cb_ = (((ks) << 5) | (kg << 3)) ^ swz; \
    _Pragma("unroll") for (int i_ = 0; i_ < 4; ++i_) \
      dst[i_] = *(const bf16x8*)&Alp[(wm * 64 + i_ * 16 + fr) * 64 + cb_]; }

#define READ_B(dst, ks) { const int cb_ = (((ks) << 5) | (kg << 3)) ^ swz; \
    _Pragma("unroll") for (int n_ = 0; n_ < 4; ++n_) \
      dst[n_] = *(const bf16x8*)&Blp[(wn * 64 + n_ * 16 + fr) * 64 + cb_]; }

#define MFMA_TILE(aset, bset) \
    _Pragma("unroll") for (int i_ = 0; i_ < 4; ++i_) \
      _Pragma("unroll") for (int n_ = 0; n_ < 4; ++n_) \
        acc[i_][n_] = __builtin_amdgcn_mfma_f32_16x16x32_bf16(aset[i_], bset[n_], acc[i_][n_], 0, 0, 0);

    STAGE(0, 0);
    for (int t = 0; t < nk; ++t) {
        asm volatile("s_waitcnt vmcnt(0)" ::: "memory");
        __builtin_amdgcn_s_barrier();
        __builtin_amdgcn_sched_barrier(0);
        if (t + 1 < nk) { STAGE(t + 1, (t + 1) & 1); __builtin_amdgcn_sched_barrier(0); }
        const u16* Alp = &lds[(t & 1) * 16384];
        const u16* Blp = Alp + 8192;
        READ_B(b0, 0); READ_A(a0, 0);
        MFMA_TILE(a0, b0);
        READ_B(b1, 1); READ_A(a1, 1);
        MFMA_TILE(a1, b1);
    }
    __builtin_amdgcn_s_barrier();

    const int cc = lane & 15;
    const int rg = lane >> 4;
    float* ep = (float*)lds + w * 1088;
    const int rcol = cc * 4;
#pragma unroll
    for (int m = 0; m < 4; ++m) {
#pragma unroll
        for (int n = 0; n < 4; ++n)
#pragma unroll
            for (int r = 0; r < 4; ++r)
                ep[(rg * 4 + r) * 68 + n * 16 + cc] = acc[m][n][r];
        asm volatile("s_waitcnt lgkmcnt(0)" ::: "memory");
        __builtin_amdgcn_sched_barrier(0);
#pragma unroll
        for (int j = 0; j < 4; ++j) {
            const int row = j * 4 + rg;
            float4 v = *(const float4*)&ep[row * 68 + rcol];
            const int gr = m0 + wm * 64 + m * 16 + row;
            *(unsigned*)&C[(size_t)gr * ldc + n0 + wn * 64 + rcol] =
                pack4_fp8(v.x * oscale, v.y * oscale, v.z * oscale, v.w * oscale);
        }
        asm volatile("s_waitcnt lgkmcnt(0)" ::: "memory");
        __builtin_amdgcn_sched_barrier(0);
    }
#undef STAGE
#undef READ_A
#undef READ_B
#undef MFMA_TILE
}

// ---------- row softmax: fp8 scores in, fp8 probs*1024 out ----------
__global__ __launch_bounds__(256)
void softmax_kernel(const u8* __restrict__ sc, u8* __restrict__ pr) {
    const size_t row = blockIdx.x;
    const u8* p = sc + row * 2048;
    const int tid = threadIdx.x;
    const int lane = tid & 63;
    const int w = tid >> 6;

    uint2 raw = *(const uint2*)&p[tid * 8];
    float v[8];
#pragma unroll
    for (int j = 0; j < 4; ++j) v[j]     = fp8_to_f32((raw.x >> (8 * j)) & 0xFF);
#pragma unroll
    for (int j = 0; j < 4; ++j) v[4 + j] = fp8_to_f32((raw.y >> (8 * j)) & 0xFF);

    float mx = v[0];
#pragma unroll
    for (int j = 1; j < 8; ++j) mx = fmaxf(mx, v[j]);
#pragma unroll
    for (int o = 32; o; o >>= 1) mx = fmaxf(mx, __shfl_xor(mx, o));

    __shared__ float red[8];
    if (!lane) red[w] = mx;
    __syncthreads();
    mx = fmaxf(fmaxf(red[0], red[1]), fmaxf(red[2], red[3]));

    float s = 0.f;
#pragma unroll
    for (int j = 0; j < 8; ++j) { v[j] = __expf(v[j] - mx); s += v[j]; }
#pragma unroll
    for (int o = 32; o; o >>= 1) s += __shfl_xor(s, o);
    if (!lane) red[4 + w] = s;
    __syncthreads();
    s = red[4] + red[5] + red[6] + red[7];
    float inv = 1024.0f / s;

    uint2 o8;
    o8.x = pack4_fp8(v[0] * inv, v[1] * inv, v[2] * inv, v[3] * inv);
    o8.y = pack4_fp8(v[4] * inv, v[5] * inv, v[6] * inv, v[7] * inv);
    *(uint2*)&pr[row * 2048 + tid * 8] = o8;
}

// ---------- in-place LayerNorm over rows of 1024 fp32 ----------
__global__ __launch_bounds__(256)
void layernorm_kernel(float* __restrict__ y,
                      const float* __restrict__ gamma,
                      const float* __restrict__ beta) {
    const size_t row = blockIdx.x;
    float* p = y + row * 1024;
    const int tid = threadIdx.x;
    const int lane = tid & 63;
    const int w = tid >> 6;

    float4 v = *(const float4*)&p[tid * 4];
    float s = v.x + v.y + v.z + v.w;
    float q = v.x * v.x + v.y * v.y + v.z * v.z + v.w * v.w;
#pragma unroll
    for (int o = 32; o; o >>= 1) { s += __shfl_xor(s, o); q += __shfl_xor(q, o); }

    __shared__ float red[16];
    if (!lane) { red[w] = s; red[8 + w] = q; }
    __syncthreads();
    s = red[0] + red[1] + red[2] + red[3];
    q = red[8] + red[9] + red[10] + red[11];

    const float mu  = s * (1.0f / 1024.0f);
    const float var = q * (1.0f / 1024.0f) - mu * mu;
    const float rs  = rsqrtf(var + 1e-5f);

    float4 g  = *(const float4*)&gamma[tid * 4];
    float4 be = *(const float4*)&beta[tid * 4];
    float4 o;
    o.x = (v.x - mu) * rs * g.x + be.x;
    o.y = (v.y - mu) * rs * g.y + be.y;
    o.z = (v.z - mu) * rs * g.z + be.z;
    o.w = (v.w - mu) * rs * g.w + be.w;
    *(float4*)&p[tid * 4] = o;
}

extern "C" void kernel_launch(void* const* d_in, const int* in_sizes, int n_in,
                              void* d_out, int out_size, void* d_ws, size_t ws_size,
                              hipStream_t stream) {
    const float* x     = (const float*)d_in[0];
    const float* Wq    = (const float*)d_in[1];
    const float* bq    = (const float*)d_in[2];
    const float* Wk    = (const float*)d_in[3];
    const float* bk    = (const float*)d_in[4];
    const float* Wv    = (const float*)d_in[5];
    const float* bv    = (const float*)d_in[6];
    const float* Wp    = (const float*)d_in[7];
    const float* bp    = (const float*)d_in[8];
    const float* gamma = (const float*)d_in[9];
    const float* beta  = (const float*)d_in[10];
    float* out = (float*)d_out;

    char* ws = (char*)d_ws;
    u8*    x8      = (u8*)(ws + 0);             // 16 MB
    u8*    q8      = (u8*)(ws + 16777216);      // 16 MB  (q8 || k8 contiguous)
    u8*    k8      = (u8*)(ws + 33554432);      // 16 MB
    u8*    vT8     = (u8*)(ws + 50331648);      // 16 MB [8][1024][2048]
    u8*    probs8  = (u8*)(ws + 67108864);      // 32 MB
    u8*    scores8 = (u8*)(ws + 100663296);     // 32 MB [8][2048][2048] fp8
    u8*    wq8     = (u8*)(ws + 167772160);     // 1 MB  (wq8||wk8||wvp8 contiguous)
    u8*    wk8     = (u8*)(ws + 168820736);     // 1 MB
    u8*    wvp8    = (u8*)(ws + 169869312);     // 1 MB
    u16*   wpb     = (u16*)(ws + 170917888);    // 2 MB
    u16*   wvT     = (u16*)(ws + 173015040);    // 2 MB
    float* bvpp    = (float*)(ws + 175112192);  // 4 KB
    float* bqk     = (float*)(ws + 175116288);  // 8 KB: bq || bk

    // concatenated q/k bias for the fused projection dispatch
    hipMemcpyAsync(bqk,        bq, 1024 * sizeof(float), hipMemcpyDeviceToDevice, stream);
    hipMemcpyAsync(bqk + 1024, bk, 1024 * sizeof(float), hipMemcpyDeviceToDevice, stream);

    // precompute Wvp (=Wp@Wv, x64 fp8) and bvpp (=Wp@bv + bp)
    cvt_kernel<<<1024, 256, 0, stream>>>(Wp, wpb, HID * HID);
    transpose_cvt_kernel<<<dim3(16, 16), 256, 0, stream>>>(Wv, wvT);
    bvp_kernel<<<256, 64, 0, stream>>>(Wp, bv, bp, bvpp);
    gemm128_kernel<<<dim3(8, 8), 256, 0, stream>>>(wpb, wvT, wvp8, HID, HID, 64.0f);

    // fused fp8 converts: x (x1), Wq (x32), Wk (x32) in one dispatch
    cvt_fp8_fused_kernel<<<18432, 256, 0, stream>>>(x, x8, Wq, wq8, Wk, wk8);

    dim3 blk(256);
    // fused q+k+vp projections: z=0 -> q8, z=1 -> k8 (fp8, bias bqk),
    // z=2 -> vT8 (transposed, scale 1/64). B strides wq8||wk8||wvp8.
    gemm_fp8_kernel<5><<<dim3(8, 128, 3), blk, 0, stream>>>(
        x8, wq8, q8, vT8, bqk, nullptr, 0.03125f, HID,
        0, (long long)HID * HID, 16777216LL, HID);

    // scores = (q.k)/32 -> fp8 (per batch)
    gemm_fp8_kernel<4><<<dim3(16, 16, 8), blk, 0, stream>>>(
        q8, k8, scores8, nullptr, nullptr, nullptr, 0.03125f, HID,
        (long long)SEQ * HID, (long long)SEQ * HID, (long long)SEQ * SEQ, SEQ);

    softmax_kernel<<<NROWS, 256, 0, stream>>>(scores8, probs8);

    // out = (probs1024 . vp)/1024 + (bvp+bp) + x  (fp32)
    gemm_fp8_kernel<2><<<dim3(8, 16, 8), blk, 0, stream>>>(
        probs8, vT8, out, nullptr, bvpp, x, 0.0009765625f, SEQ,
        (long long)SEQ * SEQ, (long long)HID * SEQ, (long long)SEQ, HID);

    layernorm_kernel<<<NROWS, 256, 0, stream>>>(out, gamma, beta);
}